// Round 3
// baseline (386.274 us; speedup 1.0000x reference)
//
#include <hip/hip_runtime.h>
#include <hip/hip_bf16.h>

#define NT 100000
#define BQ 1024
#define DD 256
#define NTILE 64
#define NTILES 1563        // ceil(100000/64)
#define GRID 1024
#define REPS 4             // accumulator replicas (atomic contention / 4)

typedef __attribute__((ext_vector_type(8))) short bf16x8;
typedef __attribute__((ext_vector_type(4))) float f32x4;

__device__ __forceinline__ unsigned f2bf(float x) {
    union { float f; unsigned u; } a; a.f = x;
    return (a.u + 0x7fffu + ((a.u >> 16) & 1u)) >> 16;  // RNE
}

// ---- init: normalize q -> bf16 (1 wave/row) + zero accumulators & counters ----
__global__ void init_k(const float* __restrict__ q, unsigned short* __restrict__ qn,
                       float* __restrict__ accs, int* __restrict__ cnts) {
    int lane = threadIdx.x & 63, wid = threadIdx.x >> 6;
    int row = blockIdx.x * 4 + wid;
    float4 v = ((const float4*)q)[(size_t)row * 64 + lane];
    float s = v.x * v.x + v.y * v.y + v.z * v.z + v.w * v.w;
    #pragma unroll
    for (int m = 1; m < 64; m <<= 1) s += __shfl_xor(s, m, 64);
    float sc = rsqrtf(fmaxf(s, 1e-24f));
    uint2 pk;
    pk.x = f2bf(v.x * sc) | (f2bf(v.y * sc) << 16);
    pk.y = f2bf(v.z * sc) | (f2bf(v.w * sc) << 16);
    *(uint2*)&qn[(size_t)row * DD + lane * 4] = pk;

    if (blockIdx.x < REPS * 8)                       // REPS * 2048 floats
        accs[blockIdx.x * 256 + threadIdx.x] = 0.f;
    if (blockIdx.x == REPS * 8 && threadIdx.x < 2)   // tile counter, done counter
        cnts[threadIdx.x] = 0;
}

// ---- main: each t-tile (64 n-rows) staged+normalized by ONE block into LDS,
// then all 8 m-chunks (full 1024 q) computed against it. A=t (D row->n),
// B=q (D col->m). Per-lane softmax partials; quad-reduce + atomics once at end;
// last finished block produces the output (done-counter pattern, no spin). ----
__global__ __launch_bounds__(256, 2) void knn_main(
        const float* __restrict__ t_raw,
        const unsigned short* __restrict__ qn,
        float* __restrict__ accs,
        int* __restrict__ cnts,
        float* __restrict__ out) {
    __shared__ unsigned short t_lds[NTILE * DD];   // 32 KB, XOR-swizzled 16B chunks
    __shared__ int s_ti;
    __shared__ int s_last;

    const int tid = threadIdx.x;
    const int lane = tid & 63, w = tid >> 6;
    const int quad = lane >> 4, l16 = lane & 15;
    const int swz = l16 & 7;

    float se[8][2] = {{0.f}}, sd[8][2] = {{0.f}};   // per-lane partials [chunk][mi]

    if (tid == 0) s_ti = atomicAdd(&cnts[0], 1);
    __syncthreads();
    int ti = s_ti;

    while (ti < NTILES) {
        const int n0 = ti * NTILE;
        // ---- stage + fused-normalize: wave w -> rows w*16..w*16+15 ----
        #pragma unroll
        for (int b = 0; b < 2; ++b) {
            float4 v[8];
            #pragma unroll
            for (int j = 0; j < 8; ++j) {
                int n = n0 + w * 16 + b * 8 + j;
                v[j] = (n < NT) ? ((const float4*)t_raw)[(size_t)n * 64 + lane]
                                : make_float4(0.f, 0.f, 0.f, 0.f);
            }
            #pragma unroll
            for (int j = 0; j < 8; ++j) {
                int r = w * 16 + b * 8 + j;
                float s = v[j].x * v[j].x + v[j].y * v[j].y + v[j].z * v[j].z + v[j].w * v[j].w;
                #pragma unroll
                for (int m = 1; m < 64; m <<= 1) s += __shfl_xor(s, m, 64);
                float sc = rsqrtf(fmaxf(s, 1e-24f));
                uint2 pk;
                pk.x = f2bf(v[j].x * sc) | (f2bf(v[j].y * sc) << 16);
                pk.y = f2bf(v[j].z * sc) | (f2bf(v[j].w * sc) << 16);
                int kb16 = lane >> 1, half = lane & 1;
                *(uint2*)&t_lds[r * DD + (((kb16 ^ (r & 7)) << 3) + (half << 2))] = pk;
            }
        }
        if (tid == 0) s_ti = atomicAdd(&cnts[0], 1);
        __syncthreads();   // B1: t_lds ready, next tile id published

        const bool full = (n0 + NTILE <= NT);
        #pragma unroll 1
        for (int c = 0; c < 8; ++c) {
            // q fragments for this m-chunk (L2-resident qn)
            bf16x8 qf[2][8];
            const unsigned short* qbase =
                qn + (size_t)(c * 128 + w * 32 + l16) * DD + quad * 8;
            #pragma unroll
            for (int mi = 0; mi < 2; ++mi)
                #pragma unroll
                for (int ks = 0; ks < 8; ++ks)
                    qf[mi][ks] = *(const bf16x8*)(qbase + mi * 16 * DD + ks * 32);

            f32x4 acc[4][2];
            #pragma unroll
            for (int ni = 0; ni < 4; ++ni)
                #pragma unroll
                for (int mi = 0; mi < 2; ++mi)
                    acc[ni][mi] = (f32x4){0.f, 0.f, 0.f, 0.f};

            #pragma unroll
            for (int ks = 0; ks < 8; ++ks) {
                bf16x8 a[4];
                #pragma unroll
                for (int ni = 0; ni < 4; ++ni)
                    a[ni] = *(const bf16x8*)
                        &t_lds[(ni * 16 + l16) * DD + (((ks * 4 + quad) ^ swz) << 3)];
                #pragma unroll
                for (int ni = 0; ni < 4; ++ni)
                    #pragma unroll
                    for (int mi = 0; mi < 2; ++mi)
                        acc[ni][mi] = __builtin_amdgcn_mfma_f32_16x16x32_bf16(
                            a[ni], qf[mi][ks], acc[ni][mi], 0, 0, 0);
            }

            // per-lane epilogue (no shuffles in the hot loop)
            if (full) {
                #pragma unroll
                for (int ni = 0; ni < 4; ++ni)
                    #pragma unroll
                    for (int mi = 0; mi < 2; ++mi)
                        #pragma unroll
                        for (int r = 0; r < 4; ++r) {
                            float d = sqrtf(fmaxf(fmaf(-2.f, acc[ni][mi][r], 2.f), 0.f));
                            float e = __expf(-10.f * d);
                            se[c][mi] += e;
                            sd[c][mi] = fmaf(e, d, sd[c][mi]);
                        }
            } else {
                #pragma unroll
                for (int ni = 0; ni < 4; ++ni)
                    #pragma unroll
                    for (int mi = 0; mi < 2; ++mi)
                        #pragma unroll
                        for (int r = 0; r < 4; ++r) {
                            float d = sqrtf(fmaxf(fmaf(-2.f, acc[ni][mi][r], 2.f), 0.f));
                            float e = (n0 + ni * 16 + quad * 4 + r < NT)
                                          ? __expf(-10.f * d) : 0.f;
                            se[c][mi] += e;
                            sd[c][mi] = fmaf(e, d, sd[c][mi]);
                        }
            }
        }
        ti = s_ti;
        __syncthreads();   // B2: all waves done reading t_lds
    }

    // ---- final quad-reduce + replicated atomic accumulate ----
    float* acc_e  = accs + (size_t)(blockIdx.x & (REPS - 1)) * 2048;
    float* acc_ed = acc_e + 1024;
    #pragma unroll
    for (int c = 0; c < 8; ++c)
        #pragma unroll
        for (int mi = 0; mi < 2; ++mi) {
            float e = se[c][mi], d = sd[c][mi];
            e += __shfl_xor(e, 16, 64); e += __shfl_xor(e, 32, 64);
            d += __shfl_xor(d, 16, 64); d += __shfl_xor(d, 32, 64);
            if (quad == 0) {
                int m0 = c * 128 + w * 32 + mi * 16 + l16;
                atomicAdd(&acc_e[m0], e);
                atomicAdd(&acc_ed[m0], d);
            }
        }

    __threadfence();
    __syncthreads();
    if (tid == 0) s_last = (atomicAdd(&cnts[1], 1) == GRID - 1) ? 1 : 0;
    __syncthreads();
    if (s_last) {
        for (int i = tid; i < BQ; i += 256) {
            float e = 0.f, d = 0.f;
            #pragma unroll
            for (int rp = 0; rp < REPS; ++rp) {
                e += __hip_atomic_load(&accs[rp * 2048 + i],
                                       __ATOMIC_RELAXED, __HIP_MEMORY_SCOPE_AGENT);
                d += __hip_atomic_load(&accs[rp * 2048 + 1024 + i],
                                       __ATOMIC_RELAXED, __HIP_MEMORY_SCOPE_AGENT);
            }
            out[i] = d / e;
        }
    }
}

extern "C" void kernel_launch(void* const* d_in, const int* in_sizes, int n_in,
                              void* d_out, int out_size, void* d_ws, size_t ws_size,
                              hipStream_t stream) {
    const float* q = (const float*)d_in[0];   // [1024,256] fp32
    const float* t = (const float*)d_in[1];   // [100000,256] fp32
    float* out = (float*)d_out;               // [1024] fp32

    char* ws = (char*)d_ws;
    float* accs = (float*)ws;                                  // REPS*2048 f = 32 KB
    int* cnts = (int*)(ws + REPS * 2048 * sizeof(float));      // 2 ints (+pad)
    unsigned short* qn = (unsigned short*)(ws + REPS * 2048 * sizeof(float) + 256);

    init_k<<<256, 256, 0, stream>>>(q, qn, accs, cnts);
    knn_main<<<GRID, 256, 0, stream>>>(t, qn, accs, cnts, out);
}